// Round 8
// baseline (300.103 us; speedup 1.0000x reference)
//
#include <hip/hip_runtime.h>

#define Bn 8
#define Cn 256
#define Hn 128
#define Wn 128
#define HW (Hn * Wn)          // 16384 = 1<<14
#define NPIX (Bn * Hn * Wn)   // 131072
#define NPAIR (NPIX / 2)      // 65536

typedef float v2f  __attribute__((ext_vector_type(2)));
typedef float v2fu __attribute__((ext_vector_type(2), aligned(4)));  // unaligned-ok float2
typedef float v4f  __attribute__((ext_vector_type(4)));

// ---------------- Kernel 1 (primary): LDS row-staged conv, double-buffered ----
// Round-7 (single-buffer LDS staging) verified the demand model: conv 80->~55us.
// This round: (a) double-buffer — stage channel-pair c+2 into buf B while
// computing pair c from buf A; ONE barrier per pair (protects B-writes and
// A-reads simultaneously; buffers disjoint -> race-free). Load latency hides
// under the 576 FMAs. (b) XCD swizzle: consecutive logical blocks -> same
// XCD's L2 (halo rows + weight slice L2-local).
// Spill guard: launch_bounds(256,6) (VGPR~80) — dbuf extends live ranges;
// round-3 lesson: spill (3x cost) is worse than 25% occupancy loss.
// Weights: s_load with chunk derived from blockIdx only (scalar; round-6
// lesson: threadIdx-derived weight indexing spills catastrophically).
#define CCH 16
#define CPC (Cn / CCH)   // 16 channels per block

__global__ __launch_bounds__(256, 6) void conv_lds_kernel(
    const float* __restrict__ x, const float* __restrict__ wconv,
    float2* __restrict__ part)
{
    __shared__ float lds[2][2][10 * Wn];  // [buf][ch][10 rows x 128] = 20 KB
    const int bid = (int)blockIdx.x;      // 0..2047
    const int swz = (bid & 7) * 256 + (bid >> 3);   // XCD-contiguous
    const int pg    = swz & 127;
    const int chunk = swz >> 7;           // 0..15 (block-uniform -> SGPR)
    const int tid = (int)threadIdx.x;
    const int lane = tid & 63;
    const int pq = pg * 256 + tid;        // pixel-quad id, 0..32767
    const int w0 = (pq & 31) << 2;
    const int b  = pq >> 12;
    const int h0 = ((pg & 15) << 3);      // first of the block's 8 rows
    const int lr = (tid >> 5);            // local row 0..7

    const float* xplane = x + ((size_t)(b * Cn + chunk * CPC)) * HW;

    const bool wm = (w0 > 0), wp = (w0 < Wn - 4);

    float a00 = 0.f, a01 = 0.f, a02 = 0.f, a03 = 0.f;   // out ch 0, px 0..3
    float a10 = 0.f, a11 = 0.f, a12 = 0.f, a13 = 0.f;   // out ch 1, px 0..3

    const float* w0b = wconv + chunk * CPC * 9;
    const float* w1b = wconv + Cn * 9 + chunk * CPC * 9;

    // stage 2 channels x 10 rows (zero-padded halo) into buffer `buf`
    auto stage = [&](int buf, int c) {
        const float* xc0 = xplane + (size_t)c * HW;
        const float* xc1 = xc0 + HW;
        #pragma unroll
        for (int k = 0; k < 5; ++k) {
            const int idx = k * 256 + tid;        // 0..1279
            const int sr  = idx >> 7;             // staged row 0..9
            const int col = idx & (Wn - 1);
            const int gr  = h0 - 1 + sr;          // global row -1..128
            const bool ok = (gr >= 0) && (gr < Hn);
            const int go  = gr * Wn + col;
            lds[buf][0][idx] = ok ? xc0[go] : 0.f;
            lds[buf][1][idx] = ok ? xc1[go] : 0.f;
        }
    };

    stage(0, 0);
    __syncthreads();

    for (int i = 0; i < 8; ++i) {
        const int c = i * 2;
        if (i < 7) stage((i + 1) & 1, c + 2);   // prefetch into other buffer

        const float* bufp = lds[i & 1][0];
        #pragma unroll
        for (int cc = 0; cc < 2; ++cc) {
            const float* base = bufp + cc * (10 * Wn);
            const float4 m0 = *(const float4*)&base[(lr + 0) * Wn + w0];
            const float4 m1 = *(const float4*)&base[(lr + 1) * Wn + w0];
            const float4 m2 = *(const float4*)&base[(lr + 2) * Wn + w0];

            // edges from neighbor lanes; boundary lanes (l%32==0/31) are
            // exactly the wm/wp-masked lanes (proven round 5)
            float l0 = __shfl(m0.w, lane - 1), r0 = __shfl(m0.x, lane + 1);
            float l1 = __shfl(m1.w, lane - 1), r1 = __shfl(m1.x, lane + 1);
            float l2 = __shfl(m2.w, lane - 1), r2 = __shfl(m2.x, lane + 1);

            float v[3][6];
            v[0][0] = wm ? l0 : 0.f; v[0][1] = m0.x; v[0][2] = m0.y;
            v[0][3] = m0.z; v[0][4] = m0.w; v[0][5] = wp ? r0 : 0.f;
            v[1][0] = wm ? l1 : 0.f; v[1][1] = m1.x; v[1][2] = m1.y;
            v[1][3] = m1.z; v[1][4] = m1.w; v[1][5] = wp ? r1 : 0.f;
            v[2][0] = wm ? l2 : 0.f; v[2][1] = m2.x; v[2][2] = m2.y;
            v[2][3] = m2.z; v[2][4] = m2.w; v[2][5] = wp ? r2 : 0.f;

            const float* w0c = w0b + (c + cc) * 9;   // scalar (s_load)
            const float* w1c = w1b + (c + cc) * 9;
            #pragma unroll
            for (int r = 0; r < 3; ++r) {
                const float k0 = w0c[r*3+0], k1 = w0c[r*3+1], k2 = w0c[r*3+2];
                const float u0 = w1c[r*3+0], u1 = w1c[r*3+1], u2 = w1c[r*3+2];
                a00 = fmaf(v[r][0], k0, a00); a00 = fmaf(v[r][1], k1, a00); a00 = fmaf(v[r][2], k2, a00);
                a01 = fmaf(v[r][1], k0, a01); a01 = fmaf(v[r][2], k1, a01); a01 = fmaf(v[r][3], k2, a01);
                a02 = fmaf(v[r][2], k0, a02); a02 = fmaf(v[r][3], k1, a02); a02 = fmaf(v[r][4], k2, a02);
                a03 = fmaf(v[r][3], k0, a03); a03 = fmaf(v[r][4], k1, a03); a03 = fmaf(v[r][5], k2, a03);
                a10 = fmaf(v[r][0], u0, a10); a10 = fmaf(v[r][1], u1, a10); a10 = fmaf(v[r][2], u2, a10);
                a11 = fmaf(v[r][1], u0, a11); a11 = fmaf(v[r][2], u1, a11); a11 = fmaf(v[r][3], u2, a11);
                a12 = fmaf(v[r][2], u0, a12); a12 = fmaf(v[r][3], u1, a12); a12 = fmaf(v[r][4], u2, a12);
                a13 = fmaf(v[r][3], u0, a13); a13 = fmaf(v[r][4], u1, a13); a13 = fmaf(v[r][5], u2, a13);
            }
        }
        // single barrier: (a) this iter's prefetch-writes visible for next
        // iter's reads; (b) this iter's reads done before next prefetch
        // overwrites the other buffer.
        __syncthreads();
    }

    v4f* pt = (v4f*)(part + (size_t)chunk * NPIX + ((size_t)pq << 2));
    v4f s0 = {a00, a10, a01, a11};
    v4f s1 = {a02, a12, a03, a13};
    pt[0] = s0;
    pt[1] = s1;
}

// ---------------- fallback conv (ws < 16 MB), round-5 form ----------------
template <int FCCH>
__global__ __launch_bounds__(256, 8) void conv_partial_kernel(
    const float* __restrict__ x, const float* __restrict__ wconv,
    float2* __restrict__ part)
{
    constexpr int FCPC = Cn / FCCH;
    const int pg    = blockIdx.x & 127;
    const int chunk = blockIdx.x >> 7;
    const int pq = pg * 256 + (int)threadIdx.x;
    const int lane = (int)threadIdx.x & 63;
    const int w0 = (pq & 31) << 2;
    const int h  = (pq >> 5) & (Hn - 1);
    const int b  = pq >> 12;

    const float* xb = x + ((size_t)(b * Cn + chunk * FCPC)) * HW + h * Wn + w0;

    const bool hm = (h > 0), hp = (h < Hn - 1);
    const bool wm = (w0 > 0), wp = (w0 < Wn - 4);

    float a00 = 0.f, a01 = 0.f, a02 = 0.f, a03 = 0.f;
    float a10 = 0.f, a11 = 0.f, a12 = 0.f, a13 = 0.f;

    const float* w0b = wconv + chunk * FCPC * 9;
    const float* w1b = wconv + Cn * 9 + chunk * FCPC * 9;

    #pragma unroll 2
    for (int c = 0; c < FCPC; ++c) {
        const float* xc = xb + c * HW;
        const float4 z4 = make_float4(0.f, 0.f, 0.f, 0.f);
        float4 m0 = hm ? *(const float4*)(xc - Wn) : z4;
        float4 m1 =      *(const float4*)(xc);
        float4 m2 = hp ? *(const float4*)(xc + Wn) : z4;

        float l0 = __shfl(m0.w, lane - 1), r0 = __shfl(m0.x, lane + 1);
        float l1 = __shfl(m1.w, lane - 1), r1 = __shfl(m1.x, lane + 1);
        float l2 = __shfl(m2.w, lane - 1), r2 = __shfl(m2.x, lane + 1);

        float v[3][6];
        v[0][0] = wm ? l0 : 0.f; v[0][1] = m0.x; v[0][2] = m0.y;
        v[0][3] = m0.z; v[0][4] = m0.w; v[0][5] = wp ? r0 : 0.f;
        v[1][0] = wm ? l1 : 0.f; v[1][1] = m1.x; v[1][2] = m1.y;
        v[1][3] = m1.z; v[1][4] = m1.w; v[1][5] = wp ? r1 : 0.f;
        v[2][0] = wm ? l2 : 0.f; v[2][1] = m2.x; v[2][2] = m2.y;
        v[2][3] = m2.z; v[2][4] = m2.w; v[2][5] = wp ? r2 : 0.f;

        const float* w0c = w0b + c * 9;
        const float* w1c = w1b + c * 9;
        #pragma unroll
        for (int r = 0; r < 3; ++r) {
            const float k0 = w0c[r*3+0], k1 = w0c[r*3+1], k2 = w0c[r*3+2];
            const float u0 = w1c[r*3+0], u1 = w1c[r*3+1], u2 = w1c[r*3+2];
            a00 = fmaf(v[r][0], k0, a00); a00 = fmaf(v[r][1], k1, a00); a00 = fmaf(v[r][2], k2, a00);
            a01 = fmaf(v[r][1], k0, a01); a01 = fmaf(v[r][2], k1, a01); a01 = fmaf(v[r][3], k2, a01);
            a02 = fmaf(v[r][2], k0, a02); a02 = fmaf(v[r][3], k1, a02); a02 = fmaf(v[r][4], k2, a02);
            a03 = fmaf(v[r][3], k0, a03); a03 = fmaf(v[r][4], k1, a03); a03 = fmaf(v[r][5], k2, a03);
            a10 = fmaf(v[r][0], u0, a10); a10 = fmaf(v[r][1], u1, a10); a10 = fmaf(v[r][2], u2, a10);
            a11 = fmaf(v[r][1], u0, a11); a11 = fmaf(v[r][2], u1, a11); a11 = fmaf(v[r][3], u2, a11);
            a12 = fmaf(v[r][2], u0, a12); a12 = fmaf(v[r][3], u1, a12); a12 = fmaf(v[r][4], u2, a12);
            a13 = fmaf(v[r][3], u0, a13); a13 = fmaf(v[r][4], u1, a13); a13 = fmaf(v[r][5], u2, a13);
        }
    }

    v4f* pt = (v4f*)(part + (size_t)chunk * NPIX + ((size_t)pq << 2));
    v4f s0 = {a00, a10, a01, a11};
    v4f s1 = {a02, a12, a03, a13};
    pt[0] = s0;
    pt[1] = s1;
}

// ---------------- Kernel 1.5: partial reduce + position (in-place) -------
template <int RCCH>
__global__ __launch_bounds__(256, 8) void reduce_kernel(
    float2* __restrict__ part, const float* __restrict__ bconv)
{
    const int pp = blockIdx.x * 256 + (int)threadIdx.x;   // 0..NPAIR-1
    v4f* p4 = (v4f*)part;
    v4f q = p4[pp];
    #pragma unroll
    for (int k = 1; k < RCCH; ++k) q += p4[(size_t)k * NPAIR + pp];

    const int pr  = pp & (HW / 2 - 1);
    const int hw0 = pr << 1;
    const int w = hw0 & (Wn - 1);
    const int h = hw0 >> 7;

    const float bc0 = bconv[0], bc1 = bconv[1];
    float px0 = (float)h + q.x + bc0;
    float py0 = (float)w + q.y + bc1;
    float px1 = (float)h + q.z + bc0;
    float py1 = (float)(w + 1) + q.w + bc1;
    px0 = fminf(fmaxf(px0, 0.f), (float)(Hn - 2));
    py0 = fminf(fmaxf(py0, 0.f), (float)(Wn - 2));
    px1 = fminf(fmaxf(px1, 0.f), (float)(Hn - 2));
    py1 = fminf(fmaxf(py1, 0.f), (float)(Wn - 2));

    v4f o = {px0, py0, px1, py1};
    p4[pp] = o;
}

// ---------------- Kernel 2: bilinear gather ----------------
// XCD swizzle: blocks covering adjacent rows (which share boundary-row
// corner reads, bs+Wn) land on the same XCD's L2 -> fills not duplicated.
#define SCH 8             // sample channel chunks
#define SPC (Cn / SCH)    // 32 channels per thread

__global__ __launch_bounds__(256, 8) void sample_kernel(
    const float* __restrict__ x, const float2* __restrict__ part,
    float* __restrict__ out)
{
    const int bid = (int)blockIdx.x;                 // 0..2047
    const int swz = (bid & 7) * 256 + (bid >> 3);    // XCD-contiguous
    const int tid = swz * 256 + (int)threadIdx.x;
    const int pp    = tid & (NPAIR - 1);
    const int chunk = tid >> 16;            // 0..7
    const int pr  = pp & (HW / 2 - 1);
    const int b   = pp >> 13;
    const int hw0 = pr << 1;

    const v4f q = ((const v4f*)part)[pp];   // px0,py0,px1,py1 (pre-clipped)

    const float fx0 = floorf(q.x), fy0 = floorf(q.y);
    const float fx1 = floorf(q.z), fy1 = floorf(q.w);
    const float dx0 = q.x - fx0, dy0 = q.y - fy0;
    const float dx1 = q.z - fx1, dy1 = q.w - fy1;
    const int bs0 = (int)fx0 * Wn + (int)fy0;
    const int bs1 = (int)fx1 * Wn + (int)fy1;

    const float glt0 = (1.f - dx0) * (1.f - dy0), grb0 = dx0 * dy0;
    const float glb0 = (1.f - dx0) * dy0,         grt0 = dx0 * (1.f - dy0);
    const float glt1 = (1.f - dx1) * (1.f - dy1), grb1 = dx1 * dy1;
    const float glb1 = (1.f - dx1) * dy1,         grt1 = dx1 * (1.f - dy1);

    const size_t cb = ((size_t)(b * Cn + chunk * SPC)) * HW;
    const float* xb = x + cb;
    float* ob = out + cb + hw0;

    #pragma unroll 8
    for (int c = 0; c < SPC; ++c) {
        const float* xc = xb + (size_t)c * HW;
        v2fu A0 = *(const v2fu*)(xc + bs0);        // lt, lb
        v2fu B0 = *(const v2fu*)(xc + bs0 + Wn);   // rt, rb
        v2fu A1 = *(const v2fu*)(xc + bs1);
        v2fu B1 = *(const v2fu*)(xc + bs1 + Wn);
        const float o0 = glt0 * A0.x + glb0 * A0.y + grt0 * B0.x + grb0 * B0.y;
        const float o1 = glt1 * A1.x + glb1 * A1.y + grt1 * B1.x + grb1 * B1.y;
        v2f o = {o0, o1};
        __builtin_nontemporal_store(o, (v2f*)(ob + (size_t)c * HW));
    }
}

extern "C" void kernel_launch(void* const* d_in, const int* in_sizes, int n_in,
                              void* d_out, int out_size, void* d_ws, size_t ws_size,
                              hipStream_t stream) {
    const float* x     = (const float*)d_in[0];
    const float* wconv = (const float*)d_in[1];
    const float* bconv = (const float*)d_in[2];
    float* out = (float*)d_out;

    float2* part = (float2*)d_ws;

    if (ws_size >= (size_t)16 * NPIX * sizeof(float2)) {
        conv_lds_kernel<<<128 * 16, 256, 0, stream>>>(x, wconv, part);
        reduce_kernel<16><<<NPAIR / 256, 256, 0, stream>>>(part, bconv);
    } else if (ws_size >= (size_t)8 * NPIX * sizeof(float2)) {
        conv_partial_kernel<8><<<128 * 8, 256, 0, stream>>>(x, wconv, part);
        reduce_kernel<8><<<NPAIR / 256, 256, 0, stream>>>(part, bconv);
    } else {
        conv_partial_kernel<4><<<128 * 4, 256, 0, stream>>>(x, wconv, part);
        reduce_kernel<4><<<NPAIR / 256, 256, 0, stream>>>(part, bconv);
    }
    sample_kernel<<<(NPAIR * SCH) / 256, 256, 0, stream>>>(x, part, out);
}

// Round 9
// 278.454 us; speedup vs baseline: 1.0777x; 1.0777x over previous
//
#include <hip/hip_runtime.h>

#define Bn 8
#define Cn 256
#define Hn 128
#define Wn 128
#define HW (Hn * Wn)          // 16384 = 1<<14
#define NPIX (Bn * Hn * Wn)   // 131072
#define NPAIR (NPIX / 2)      // 65536

typedef float v2f  __attribute__((ext_vector_type(2)));
typedef float v2fu __attribute__((ext_vector_type(2), aligned(4)));  // unaligned-ok float2
typedef float v4f  __attribute__((ext_vector_type(4)));

// ---------------- Kernel 1 (primary): LDS row-staged conv ----------------
// ROUND-7 FORM, verbatim — proven ~55us. Round-8 taught:
//  - double-buffer + launch_bounds(256,6) REGRESSED to 80us (occupancy 45%,
//    and the prefetch's ds_writes (dependent on global loads) sit before the
//    FMA block in program order -> vmcnt wait still exposed). Do not re-try
//    without making the stage truly sink past compute.
//  - XCD swizzle on conv: untested in isolation; round-7 form had none.
// Demand model (verified round 7): stage 10 rows (8+2 halo) once per channel
// -> row re-reads 3x -> 1.25x, conv 80 -> ~55us.
#define CCH 16
#define CPC (Cn / CCH)   // 16 channels per block

__global__ __launch_bounds__(256, 8) void conv_lds_kernel(
    const float* __restrict__ x, const float* __restrict__ wconv,
    float2* __restrict__ part)
{
    __shared__ float lds[2][10 * Wn];     // 2 channels x 10 rows x 128 cols
    const int pg    = blockIdx.x & 127;   // 128 pixel groups of 1024 px
    const int chunk = blockIdx.x >> 7;    // 0..15 (scalar)
    const int tid = (int)threadIdx.x;
    const int lane = tid & 63;
    const int pq = pg * 256 + tid;        // pixel-quad id, 0..32767
    const int w0 = (pq & 31) << 2;
    const int b  = pq >> 12;
    const int h0 = ((pg & 15) << 3);      // first of the block's 8 rows
    const int lr = (tid >> 5);            // local row 0..7 (h = h0+lr)

    const float* xplane = x + ((size_t)(b * Cn + chunk * CPC)) * HW;

    const bool wm = (w0 > 0), wp = (w0 < Wn - 4);

    float a00 = 0.f, a01 = 0.f, a02 = 0.f, a03 = 0.f;   // out ch 0, px 0..3
    float a10 = 0.f, a11 = 0.f, a12 = 0.f, a13 = 0.f;   // out ch 1, px 0..3

    const float* w0b = wconv + chunk * CPC * 9;
    const float* w1b = wconv + Cn * 9 + chunk * CPC * 9;

    for (int c = 0; c < CPC; c += 2) {
        // ---- stage 2 channels x 10 rows (zero-padded halo) ----
        const float* xc0 = xplane + (size_t)c * HW;
        const float* xc1 = xc0 + HW;
        #pragma unroll
        for (int k = 0; k < 5; ++k) {
            const int idx = k * 256 + tid;        // 0..1279
            const int sr  = idx >> 7;             // staged row 0..9
            const int col = idx & (Wn - 1);
            const int gr  = h0 - 1 + sr;          // global row -1..128
            const bool ok = (gr >= 0) && (gr < Hn);
            const int go  = gr * Wn + col;
            lds[0][idx] = ok ? xc0[go] : 0.f;
            lds[1][idx] = ok ? xc1[go] : 0.f;
        }
        __syncthreads();

        #pragma unroll
        for (int cc = 0; cc < 2; ++cc) {
            const float* base = lds[cc];
            // window rows lr..lr+2 (staged row 0 = global h0-1)
            const float4 m0 = *(const float4*)&base[(lr + 0) * Wn + w0];
            const float4 m1 = *(const float4*)&base[(lr + 1) * Wn + w0];
            const float4 m2 = *(const float4*)&base[(lr + 2) * Wn + w0];

            // edges from neighbor lanes; boundary lanes (l%32==0/31) are
            // exactly the wm/wp-masked lanes (proven round 5)
            float l0 = __shfl(m0.w, lane - 1), r0 = __shfl(m0.x, lane + 1);
            float l1 = __shfl(m1.w, lane - 1), r1 = __shfl(m1.x, lane + 1);
            float l2 = __shfl(m2.w, lane - 1), r2 = __shfl(m2.x, lane + 1);

            float v[3][6];
            v[0][0] = wm ? l0 : 0.f; v[0][1] = m0.x; v[0][2] = m0.y;
            v[0][3] = m0.z; v[0][4] = m0.w; v[0][5] = wp ? r0 : 0.f;
            v[1][0] = wm ? l1 : 0.f; v[1][1] = m1.x; v[1][2] = m1.y;
            v[1][3] = m1.z; v[1][4] = m1.w; v[1][5] = wp ? r1 : 0.f;
            v[2][0] = wm ? l2 : 0.f; v[2][1] = m2.x; v[2][2] = m2.y;
            v[2][3] = m2.z; v[2][4] = m2.w; v[2][5] = wp ? r2 : 0.f;

            const float* w0c = w0b + (c + cc) * 9;   // scalar (s_load)
            const float* w1c = w1b + (c + cc) * 9;
            #pragma unroll
            for (int r = 0; r < 3; ++r) {
                const float k0 = w0c[r*3+0], k1 = w0c[r*3+1], k2 = w0c[r*3+2];
                const float u0 = w1c[r*3+0], u1 = w1c[r*3+1], u2 = w1c[r*3+2];
                a00 = fmaf(v[r][0], k0, a00); a00 = fmaf(v[r][1], k1, a00); a00 = fmaf(v[r][2], k2, a00);
                a01 = fmaf(v[r][1], k0, a01); a01 = fmaf(v[r][2], k1, a01); a01 = fmaf(v[r][3], k2, a01);
                a02 = fmaf(v[r][2], k0, a02); a02 = fmaf(v[r][3], k1, a02); a02 = fmaf(v[r][4], k2, a02);
                a03 = fmaf(v[r][3], k0, a03); a03 = fmaf(v[r][4], k1, a03); a03 = fmaf(v[r][5], k2, a03);
                a10 = fmaf(v[r][0], u0, a10); a10 = fmaf(v[r][1], u1, a10); a10 = fmaf(v[r][2], u2, a10);
                a11 = fmaf(v[r][1], u0, a11); a11 = fmaf(v[r][2], u1, a11); a11 = fmaf(v[r][3], u2, a11);
                a12 = fmaf(v[r][2], u0, a12); a12 = fmaf(v[r][3], u1, a12); a12 = fmaf(v[r][4], u2, a12);
                a13 = fmaf(v[r][3], u0, a13); a13 = fmaf(v[r][4], u1, a13); a13 = fmaf(v[r][5], u2, a13);
            }
        }
        __syncthreads();   // protect lds before next stage overwrites
    }

    v4f* pt = (v4f*)(part + (size_t)chunk * NPIX + ((size_t)pq << 2));
    v4f s0 = {a00, a10, a01, a11};
    v4f s1 = {a02, a12, a03, a13};
    pt[0] = s0;
    pt[1] = s1;
}

// ---------------- fallback conv (ws < 16 MB), round-5 form ----------------
template <int FCCH>
__global__ __launch_bounds__(256, 8) void conv_partial_kernel(
    const float* __restrict__ x, const float* __restrict__ wconv,
    float2* __restrict__ part)
{
    constexpr int FCPC = Cn / FCCH;
    const int pg    = blockIdx.x & 127;
    const int chunk = blockIdx.x >> 7;
    const int pq = pg * 256 + (int)threadIdx.x;
    const int lane = (int)threadIdx.x & 63;
    const int w0 = (pq & 31) << 2;
    const int h  = (pq >> 5) & (Hn - 1);
    const int b  = pq >> 12;

    const float* xb = x + ((size_t)(b * Cn + chunk * FCPC)) * HW + h * Wn + w0;

    const bool hm = (h > 0), hp = (h < Hn - 1);
    const bool wm = (w0 > 0), wp = (w0 < Wn - 4);

    float a00 = 0.f, a01 = 0.f, a02 = 0.f, a03 = 0.f;
    float a10 = 0.f, a11 = 0.f, a12 = 0.f, a13 = 0.f;

    const float* w0b = wconv + chunk * FCPC * 9;
    const float* w1b = wconv + Cn * 9 + chunk * FCPC * 9;

    #pragma unroll 2
    for (int c = 0; c < FCPC; ++c) {
        const float* xc = xb + c * HW;
        const float4 z4 = make_float4(0.f, 0.f, 0.f, 0.f);
        float4 m0 = hm ? *(const float4*)(xc - Wn) : z4;
        float4 m1 =      *(const float4*)(xc);
        float4 m2 = hp ? *(const float4*)(xc + Wn) : z4;

        float l0 = __shfl(m0.w, lane - 1), r0 = __shfl(m0.x, lane + 1);
        float l1 = __shfl(m1.w, lane - 1), r1 = __shfl(m1.x, lane + 1);
        float l2 = __shfl(m2.w, lane - 1), r2 = __shfl(m2.x, lane + 1);

        float v[3][6];
        v[0][0] = wm ? l0 : 0.f; v[0][1] = m0.x; v[0][2] = m0.y;
        v[0][3] = m0.z; v[0][4] = m0.w; v[0][5] = wp ? r0 : 0.f;
        v[1][0] = wm ? l1 : 0.f; v[1][1] = m1.x; v[1][2] = m1.y;
        v[1][3] = m1.z; v[1][4] = m1.w; v[1][5] = wp ? r1 : 0.f;
        v[2][0] = wm ? l2 : 0.f; v[2][1] = m2.x; v[2][2] = m2.y;
        v[2][3] = m2.z; v[2][4] = m2.w; v[2][5] = wp ? r2 : 0.f;

        const float* w0c = w0b + c * 9;
        const float* w1c = w1b + c * 9;
        #pragma unroll
        for (int r = 0; r < 3; ++r) {
            const float k0 = w0c[r*3+0], k1 = w0c[r*3+1], k2 = w0c[r*3+2];
            const float u0 = w1c[r*3+0], u1 = w1c[r*3+1], u2 = w1c[r*3+2];
            a00 = fmaf(v[r][0], k0, a00); a00 = fmaf(v[r][1], k1, a00); a00 = fmaf(v[r][2], k2, a00);
            a01 = fmaf(v[r][1], k0, a01); a01 = fmaf(v[r][2], k1, a01); a01 = fmaf(v[r][3], k2, a01);
            a02 = fmaf(v[r][2], k0, a02); a02 = fmaf(v[r][3], k1, a02); a02 = fmaf(v[r][4], k2, a02);
            a03 = fmaf(v[r][3], k0, a03); a03 = fmaf(v[r][4], k1, a03); a03 = fmaf(v[r][5], k2, a03);
            a10 = fmaf(v[r][0], u0, a10); a10 = fmaf(v[r][1], u1, a10); a10 = fmaf(v[r][2], u2, a10);
            a11 = fmaf(v[r][1], u0, a11); a11 = fmaf(v[r][2], u1, a11); a11 = fmaf(v[r][3], u2, a11);
            a12 = fmaf(v[r][2], u0, a12); a12 = fmaf(v[r][3], u1, a12); a12 = fmaf(v[r][4], u2, a12);
            a13 = fmaf(v[r][3], u0, a13); a13 = fmaf(v[r][4], u1, a13); a13 = fmaf(v[r][5], u2, a13);
        }
    }

    v4f* pt = (v4f*)(part + (size_t)chunk * NPIX + ((size_t)pq << 2));
    v4f s0 = {a00, a10, a01, a11};
    v4f s1 = {a02, a12, a03, a13};
    pt[0] = s0;
    pt[1] = s1;
}

// ---------------- Kernel 1.5: partial reduce + position (in-place) -------
template <int RCCH>
__global__ __launch_bounds__(256, 8) void reduce_kernel(
    float2* __restrict__ part, const float* __restrict__ bconv)
{
    const int pp = blockIdx.x * 256 + (int)threadIdx.x;   // 0..NPAIR-1
    v4f* p4 = (v4f*)part;
    v4f q = p4[pp];
    #pragma unroll
    for (int k = 1; k < RCCH; ++k) q += p4[(size_t)k * NPAIR + pp];

    const int pr  = pp & (HW / 2 - 1);
    const int hw0 = pr << 1;
    const int w = hw0 & (Wn - 1);
    const int h = hw0 >> 7;

    const float bc0 = bconv[0], bc1 = bconv[1];
    float px0 = (float)h + q.x + bc0;
    float py0 = (float)w + q.y + bc1;
    float px1 = (float)h + q.z + bc0;
    float py1 = (float)(w + 1) + q.w + bc1;
    px0 = fminf(fmaxf(px0, 0.f), (float)(Hn - 2));
    py0 = fminf(fmaxf(py0, 0.f), (float)(Wn - 2));
    px1 = fminf(fmaxf(px1, 0.f), (float)(Hn - 2));
    py1 = fminf(fmaxf(py1, 0.f), (float)(Wn - 2));

    v4f o = {px0, py0, px1, py1};
    p4[pp] = o;
}

// ---------------- Kernel 2: bilinear gather ----------------
// XCD swizzle KEPT (round-8 decomposition: sample+reduce improved ~10us
// with it — each XCD owns one 32-channel chunk of all pixels, gather rows
// L2-local).
#define SCH 8             // sample channel chunks
#define SPC (Cn / SCH)    // 32 channels per thread

__global__ __launch_bounds__(256, 8) void sample_kernel(
    const float* __restrict__ x, const float2* __restrict__ part,
    float* __restrict__ out)
{
    const int bid = (int)blockIdx.x;                 // 0..2047
    const int swz = (bid & 7) * 256 + (bid >> 3);    // XCD-contiguous
    const int tid = swz * 256 + (int)threadIdx.x;
    const int pp    = tid & (NPAIR - 1);
    const int chunk = tid >> 16;            // 0..7
    const int pr  = pp & (HW / 2 - 1);
    const int b   = pp >> 13;
    const int hw0 = pr << 1;

    const v4f q = ((const v4f*)part)[pp];   // px0,py0,px1,py1 (pre-clipped)

    const float fx0 = floorf(q.x), fy0 = floorf(q.y);
    const float fx1 = floorf(q.z), fy1 = floorf(q.w);
    const float dx0 = q.x - fx0, dy0 = q.y - fy0;
    const float dx1 = q.z - fx1, dy1 = q.w - fy1;
    const int bs0 = (int)fx0 * Wn + (int)fy0;
    const int bs1 = (int)fx1 * Wn + (int)fy1;

    const float glt0 = (1.f - dx0) * (1.f - dy0), grb0 = dx0 * dy0;
    const float glb0 = (1.f - dx0) * dy0,         grt0 = dx0 * (1.f - dy0);
    const float glt1 = (1.f - dx1) * (1.f - dy1), grb1 = dx1 * dy1;
    const float glb1 = (1.f - dx1) * dy1,         grt1 = dx1 * (1.f - dy1);

    const size_t cb = ((size_t)(b * Cn + chunk * SPC)) * HW;
    const float* xb = x + cb;
    float* ob = out + cb + hw0;

    #pragma unroll 8
    for (int c = 0; c < SPC; ++c) {
        const float* xc = xb + (size_t)c * HW;
        v2fu A0 = *(const v2fu*)(xc + bs0);        // lt, lb
        v2fu B0 = *(const v2fu*)(xc + bs0 + Wn);   // rt, rb
        v2fu A1 = *(const v2fu*)(xc + bs1);
        v2fu B1 = *(const v2fu*)(xc + bs1 + Wn);
        const float o0 = glt0 * A0.x + glb0 * A0.y + grt0 * B0.x + grb0 * B0.y;
        const float o1 = glt1 * A1.x + glb1 * A1.y + grt1 * B1.x + grb1 * B1.y;
        v2f o = {o0, o1};
        __builtin_nontemporal_store(o, (v2f*)(ob + (size_t)c * HW));
    }
}

extern "C" void kernel_launch(void* const* d_in, const int* in_sizes, int n_in,
                              void* d_out, int out_size, void* d_ws, size_t ws_size,
                              hipStream_t stream) {
    const float* x     = (const float*)d_in[0];
    const float* wconv = (const float*)d_in[1];
    const float* bconv = (const float*)d_in[2];
    float* out = (float*)d_out;

    float2* part = (float2*)d_ws;

    if (ws_size >= (size_t)16 * NPIX * sizeof(float2)) {
        conv_lds_kernel<<<128 * 16, 256, 0, stream>>>(x, wconv, part);
        reduce_kernel<16><<<NPAIR / 256, 256, 0, stream>>>(part, bconv);
    } else if (ws_size >= (size_t)8 * NPIX * sizeof(float2)) {
        conv_partial_kernel<8><<<128 * 8, 256, 0, stream>>>(x, wconv, part);
        reduce_kernel<8><<<NPAIR / 256, 256, 0, stream>>>(part, bconv);
    } else {
        conv_partial_kernel<4><<<128 * 4, 256, 0, stream>>>(x, wconv, part);
        reduce_kernel<4><<<NPAIR / 256, 256, 0, stream>>>(part, bconv);
    }
    sample_kernel<<<(NPAIR * SCH) / 256, 256, 0, stream>>>(x, part, out);
}